// Round 6
// baseline (455.388 us; speedup 1.0000x reference)
//
#include <hip/hip_runtime.h>
#include <hip/hip_bf16.h>

// GCN forward: 5x (agg + linear + relu fused) + segment_max pool + MLP head.
// N=100000, E=1600000, C=32, G=128.
//
//  - CSR build via 2-level binning sort (bucket = dst>>7). NO per-node global
//    atomics anywhere:
//      bucket_count: per-chunk LDS hist (782 buckets) -> global btot adds.
//      bin_kernel:   LDS hist reserves contiguous per-(block,bucket) runs,
//                    writes packed (dstLocal<<20|src) pairs in ~64B runs.
//      node_count:   per bucket, LDS 128-ctr hist of pairs -> cnt/dinvx/xi2.
//      csr_scatter:  per bucket, LDS cursors from offsets4 -> csr (+pad to x4
//                    with index N, an all-zero feature row).
//  - features stored pre-scaled: ht[i] = dinv[i] * h[i]; ht[N] = 0.
//  - fused layer: 32-lane group per node, quad-gather layout: lane =
//    (sub=lane>>3, c4=lane&7); one gather instruction fetches 4 edges' rows
//    (8 lanes x float4 per row) -> 2 VMEM inst per 4 edges instead of 5,
//    4 independent latency chains. shfl_xor reduce over edge slots, then
//    in-register 32x32 matmul via __shfl, relu, optional dinv pre-scale.
//  - pool: chunked running-max over sorted batch, uint atomicMax flush.
//  - head: 32-lane group per graph, float4 weight rows + __shfl matmul.

#define CDIM 32
#define BSHIFT 7
#define BSPAN 128
#define MAXBUK 800      // >= ceil(100000/128)=782
#define CHUNK 12800

// per-chunk LDS histogram of dst buckets -> btot
__global__ void __launch_bounds__(256) bucket_count(
    const int* __restrict__ edst, int* __restrict__ btot, int E, int nbuk) {
    __shared__ int hist[MAXBUK];
    int t = threadIdx.x;
    int base = blockIdx.x * CHUNK;
    int n = min(CHUNK, E - base);
    if (n <= 0) return;
    for (int i = t; i < nbuk; i += 256) hist[i] = 0;
    __syncthreads();
    for (int i = t; i < n; i += 256)
        atomicAdd(&hist[edst[base + i] >> BSHIFT], 1);
    __syncthreads();
    for (int b = t; b < nbuk; b += 256) {
        int h = hist[b];
        if (h) atomicAdd(&btot[b], h);
    }
}

// single block, 1024 threads; exclusive scan of btot -> bbase, gcursor
__global__ void bscan_kernel(const int* __restrict__ btot, int* __restrict__ bbase,
                             int* __restrict__ gcursor, int nb) {
    __shared__ int s[1024];
    int t = threadIdx.x;
    int v = (t < nb) ? btot[t] : 0;
    s[t] = v;
    __syncthreads();
    for (int d = 1; d < 1024; d <<= 1) {
        int x = (t >= d) ? s[t - d] : 0;
        __syncthreads();
        s[t] += x;
        __syncthreads();
    }
    if (t < nb) {
        bbase[t] = s[t] - v;
        gcursor[t] = s[t] - v;
    }
}

// bin edges by dst>>BSHIFT; contiguous per-(block,bucket) runs in pairs[]
__global__ void __launch_bounds__(256) bin_kernel(
    const int* __restrict__ esrc, const int* __restrict__ edst,
    int* __restrict__ gcursor, unsigned* __restrict__ pairs, int E, int nbuk) {
    __shared__ int hist[MAXBUK];
    __shared__ int lcur[MAXBUK];
    int t = threadIdx.x;
    int base = blockIdx.x * CHUNK;
    int n = min(CHUNK, E - base);
    if (n <= 0) return;
    for (int i = t; i < nbuk; i += 256) hist[i] = 0;
    __syncthreads();
    for (int i = t; i < n; i += 256)
        atomicAdd(&hist[edst[base + i] >> BSHIFT], 1);
    __syncthreads();
    for (int b = t; b < nbuk; b += 256) {
        int h = hist[b];
        lcur[b] = h ? atomicAdd(&gcursor[b], h) : 0;
    }
    __syncthreads();
    for (int i = t; i < n; i += 256) {
        int d = edst[base + i];
        int s = esrc[base + i];
        int b = d >> BSHIFT;
        int pos = atomicAdd(&lcur[b], 1);
        pairs[pos] = ((unsigned)(d & (BSPAN - 1)) << 20) | (unsigned)s;
    }
}

// per bucket: LDS histogram of dstLocal -> cnt, dinvx, xi2 (coalesced writes)
__global__ void __launch_bounds__(256) node_count(
    const unsigned* __restrict__ pairs, const int* __restrict__ bbase,
    const int* __restrict__ btot, const int* __restrict__ x_idx,
    int* __restrict__ cnt, float* __restrict__ dinvx, int* __restrict__ xi2,
    int N) {
    __shared__ int h[BSPAN];
    int b = blockIdx.x, t = threadIdx.x;
    if (t < BSPAN) h[t] = 0;
    __syncthreads();
    int p0 = bbase[b], p1 = p0 + btot[b];
    for (int i = p0 + t; i < p1; i += 256)
        atomicAdd(&h[pairs[i] >> 20], 1);
    __syncthreads();
    if (t < BSPAN) {
        int v = (b << BSHIFT) + t;
        if (v < N) {
            int c = h[t];
            cnt[v] = c;
            dinvx[v] = rsqrtf((float)c + 1.0f);
            xi2[v] = x_idx[v];
        }
    }
    if (b == 0 && t == 255) {  // sentinel row N
        dinvx[N] = 0.f;
        xi2[N] = 0;
    }
}

// padded-count scans: value = (cnt+3)&~3
__global__ void scan_reduce(const int* __restrict__ cnt, int* __restrict__ bsums, int N) {
    __shared__ int s[256];
    int t = threadIdx.x;
    int i = blockIdx.x * 256 + t;
    s[t] = (i < N) ? ((cnt[i] + 3) & ~3) : 0;
    __syncthreads();
    for (int d = 128; d > 0; d >>= 1) {
        if (t < d) s[t] += s[t + d];
        __syncthreads();
    }
    if (t == 0) bsums[blockIdx.x] = s[0];
}

__global__ void scan_bsums(int* bsums, int nb) {
    __shared__ int s[512];
    int t = threadIdx.x;
    int v = (t < nb) ? bsums[t] : 0;
    s[t] = v;
    __syncthreads();
    for (int d = 1; d < 512; d <<= 1) {
        int x = (t >= d) ? s[t - d] : 0;
        __syncthreads();
        s[t] += x;
        __syncthreads();
    }
    if (t < nb) bsums[t] = s[t] - v;  // exclusive
}

__global__ void scan_final(const int* __restrict__ cnt, const int* __restrict__ bsums,
                           int* __restrict__ offsets4, int N) {
    __shared__ int s[256];
    int t = threadIdx.x;
    int i = blockIdx.x * 256 + t;
    int v = (i < N) ? ((cnt[i] + 3) & ~3) : 0;
    s[t] = v;
    __syncthreads();
    for (int d = 1; d < 256; d <<= 1) {
        int x = (t >= d) ? s[t - d] : 0;
        __syncthreads();
        s[t] += x;
        __syncthreads();
    }
    if (i < N) offsets4[i] = s[t] - v + bsums[blockIdx.x];
}

// per bucket: scatter src into padded CSR via LDS cursors; pad to x4 with N
__global__ void __launch_bounds__(256) csr_scatter(
    const unsigned* __restrict__ pairs, const int* __restrict__ bbase,
    const int* __restrict__ btot, const int* __restrict__ offsets4,
    int* __restrict__ csr, int N) {
    __shared__ int lcur[BSPAN];
    __shared__ int obase[BSPAN];
    int b = blockIdx.x, t = threadIdx.x;
    int v0 = b << BSHIFT;
    if (t < BSPAN) {
        int v = v0 + t;
        int o = (v < N) ? offsets4[v] : 0;
        lcur[t] = o;
        obase[t] = o;
    }
    __syncthreads();
    int p0 = bbase[b], p1 = p0 + btot[b];
    for (int i = p0 + t; i < p1; i += 256) {
        unsigned pk = pairs[i];
        int pos = atomicAdd(&lcur[pk >> 20], 1);
        csr[pos] = (int)(pk & 0xFFFFFu);
    }
    __syncthreads();
    if (t < BSPAN) {
        int v = v0 + t;
        if (v < N) {
            int e = lcur[t];  // == offsets4[v] + cnt[v]
            int e1 = obase[t] + ((e - obase[t] + 3) & ~3);
            for (; e < e1; ++e) csr[e] = N;  // pad -> zero feature row
        }
    }
}

// Fused GCN layer, quad-gather layout: one gather inst = 4 edges per group.
template <bool L1>
__global__ void __launch_bounds__(256) gcn_layer(
    const float* __restrict__ ht, const int* __restrict__ xi2,
    const float* __restrict__ ew, const float* __restrict__ dinvx,
    const int* __restrict__ offsets4, const int* __restrict__ cnt,
    const int* __restrict__ csr, const float* __restrict__ W,
    const float* __restrict__ bias, float* __restrict__ out,
    int N, int scale_next) {
    int c = threadIdx.x & 31;   // output channel (matmul/store layout)
    int grp = threadIdx.x >> 5; // 0..7: node group within block
    int c4 = c & 7;             // channel quad (gather layout)
    int sub = c >> 3;           // edge slot 0..3 (gather layout)

    float w[CDIM];
    {
        const float4* Wrow = reinterpret_cast<const float4*>(W + c * CDIM);
        #pragma unroll
        for (int q = 0; q < CDIM / 4; ++q) {
            float4 t = Wrow[q];
            w[4 * q + 0] = t.x;
            w[4 * q + 1] = t.y;
            w[4 * q + 2] = t.z;
            w[4 * q + 3] = t.w;
        }
    }
    float bc = bias[c];

    const float4* ht4 = reinterpret_cast<const float4*>(ht);
    const float4* ew4 = reinterpret_cast<const float4*>(ew);

    for (int v0 = blockIdx.x * 8; v0 < N; v0 += gridDim.x * 8) {
        int v = v0 + grp;
        if (v >= N) continue;  // uniform across the 32-lane group
        float dv = dinvx[v];
        float ax = 0.f, ay = 0.f, az = 0.f, aw = 0.f;
        int e = offsets4[v];
        int e1 = e + ((cnt[v] + 3) & ~3);
        for (; e < e1; e += 4) {
            int s = csr[e + sub];      // 4 distinct ints, broadcast to 8 lanes
            if (L1) {
                float ds = dinvx[s];
                float4 q = ew4[xi2[s] * 8 + c4];
                ax = fmaf(ds, q.x, ax);
                ay = fmaf(ds, q.y, ay);
                az = fmaf(ds, q.z, az);
                aw = fmaf(ds, q.w, aw);
            } else {
                float4 q = ht4[s * 8 + c4];
                ax += q.x; ay += q.y; az += q.z; aw += q.w;
            }
        }
        // reduce the 4 edge slots (xor over lane bits 3,4)
        ax += __shfl_xor(ax, 8, 32);
        ay += __shfl_xor(ay, 8, 32);
        az += __shfl_xor(az, 8, 32);
        aw += __shfl_xor(aw, 8, 32);
        ax += __shfl_xor(ax, 16, 32);
        ay += __shfl_xor(ay, 16, 32);
        az += __shfl_xor(az, 16, 32);
        aw += __shfl_xor(aw, 16, 32);
        // self term (stored pre-scaled; for L1 scale the embed row by dv)
        if (L1) {
            float4 q = ew4[xi2[v] * 8 + c4];
            ax = fmaf(dv, q.x, ax);
            ay = fmaf(dv, q.y, ay);
            az = fmaf(dv, q.z, az);
            aw = fmaf(dv, q.w, aw);
        } else {
            float4 q = ht4[v * 8 + c4];
            ax += q.x; ay += q.y; az += q.z; aw += q.w;
        }
        ax *= dv; ay *= dv; az *= dv; aw *= dv;
        // redistribute quad layout -> scalar channel per lane
        int srcl = c >> 2;
        float t0 = __shfl(ax, srcl, 32);
        float t1 = __shfl(ay, srcl, 32);
        float t2 = __shfl(az, srcl, 32);
        float t3 = __shfl(aw, srcl, 32);
        float aggv = (c & 2) ? ((c & 1) ? t3 : t2) : ((c & 1) ? t1 : t0);
        float o = bc;
        #pragma unroll
        for (int k = 0; k < CDIM; ++k)
            o = fmaf(__shfl(aggv, k, 32), w[k], o);
        o = fmaxf(o, 0.f);
        if (scale_next) o *= dv;
        out[v * CDIM + c] = o;
    }
}

// chunked segment-max over sorted batch; h >= 0 so uint-bit atomicMax is valid
#define PCHUNK 128
__global__ void pool_kernel(const float* __restrict__ h, const int* __restrict__ batch,
                            unsigned* __restrict__ pooled, int N) {
    __shared__ int sb[8 * PCHUNK];
    int t = threadIdx.x;
    int chunk0 = blockIdx.x * 8;
    int sbase = chunk0 * PCHUNK;
    for (int i = t; i < 8 * PCHUNK; i += 256)
        sb[i] = (sbase + i < N) ? batch[sbase + i] : -1;
    __syncthreads();
    int c = t & 31, cs = t >> 5;
    int i0 = (chunk0 + cs) * PCHUNK;
    if (i0 >= N) return;
    int curg = sb[cs * PCHUNK];
    float m = -1.0f;  // sentinel: nothing accumulated (h values are >= 0)
    for (int k = 0; k < PCHUNK; ++k) {
        int i = i0 + k;
        if (i >= N) break;
        int g = sb[cs * PCHUNK + k];
        float v = h[i * CDIM + c];
        if (g != curg) {
            if (m >= 0.f) atomicMax(&pooled[curg * CDIM + c], __float_as_uint(m));
            curg = g;
            m = v;
        } else {
            m = fmaxf(m, v);
        }
    }
    if (m >= 0.f && curg >= 0) atomicMax(&pooled[curg * CDIM + c], __float_as_uint(m));
}

// 32-lane group per graph; coalesced float4 weight rows + __shfl matmul.
__global__ void __launch_bounds__(256) head_kernel(
    const float* __restrict__ pooled,
    const float* __restrict__ d0_w, const float* __restrict__ d0_b,
    const float* __restrict__ dense_w, const float* __restrict__ dense_b,
    const float* __restrict__ fin_w, const float* __restrict__ fin_b,
    float* __restrict__ out, int G) {
    int c = threadIdx.x & 31;
    int grp = threadIdx.x >> 5;
    int g = blockIdx.x * 8 + grp;
    if (g >= G) return;

    float x = pooled[g * CDIM + c];  // lane c holds channel c

    const float* Ws[4] = {d0_w, dense_w, dense_w + CDIM * CDIM,
                          dense_w + 2 * CDIM * CDIM};
    const float* bs[4] = {d0_b, dense_b, dense_b + CDIM, dense_b + 2 * CDIM};
    for (int l = 0; l < 4; ++l) {
        float w[CDIM];
        const float4* Wrow = reinterpret_cast<const float4*>(Ws[l] + c * CDIM);
        #pragma unroll
        for (int q = 0; q < CDIM / 4; ++q) {
            float4 t = Wrow[q];
            w[4 * q + 0] = t.x;
            w[4 * q + 1] = t.y;
            w[4 * q + 2] = t.z;
            w[4 * q + 3] = t.w;
        }
        float acc = bs[l][c];
        #pragma unroll
        for (int k = 0; k < CDIM; ++k)
            acc = fmaf(__shfl(x, k, 32), w[k], acc);
        x = fmaxf(acc, 0.f);
    }
    // logits: butterfly reduce partial products across the 32-lane group
    float p0 = x * fin_w[c];
    float p1 = x * fin_w[CDIM + c];
    #pragma unroll
    for (int d = 16; d > 0; d >>= 1) {
        p0 += __shfl_xor(p0, d, 32);
        p1 += __shfl_xor(p1, d, 32);
    }
    float l0 = p0 + fin_b[0], l1 = p1 + fin_b[1];
    float mm = fmaxf(l0, l1);
    float lse = mm + logf(expf(l0 - mm) + expf(l1 - mm));
    if (c == 0) {
        out[g * 2 + 0] = l0 - lse;
        out[g * 2 + 1] = l1 - lse;
    }
}

extern "C" void kernel_launch(void* const* d_in, const int* in_sizes, int n_in,
                              void* d_out, int out_size, void* d_ws, size_t ws_size,
                              hipStream_t stream) {
    const int* x_idx = (const int*)d_in[0];
    const int* eidx = (const int*)d_in[1];
    const int* batch = (const int*)d_in[2];
    const float* embed_w = (const float*)d_in[3];
    const float* conv_w = (const float*)d_in[4];
    const float* conv_b = (const float*)d_in[5];
    const float* d0_w = (const float*)d_in[6];
    const float* d0_b = (const float*)d_in[7];
    const float* dense_w = (const float*)d_in[8];
    const float* dense_b = (const float*)d_in[9];
    const float* fin_w = (const float*)d_in[10];
    const float* fin_b = (const float*)d_in[11];

    int N = in_sizes[0];
    int E = in_sizes[1] / 2;
    int G = out_size / 2;
    const int* esrc = eidx;
    const int* edst = eidx + E;
    int nbuk = (N + BSPAN - 1) >> BSHIFT;  // 782

    char* ws = (char*)d_ws;
    size_t off = 0;
    auto take = [&](size_t bytes) -> char* {
        char* p = ws + off;
        off = (off + bytes + 255) & ~(size_t)255;
        return p;
    };
    int* cnt = (int*)take((size_t)N * 4);
    float* dinvx = (float*)take((size_t)(N + 1) * 4);
    int* xi2 = (int*)take((size_t)(N + 1) * 4);
    int* offsets4 = (int*)take((size_t)N * 4);
    int* bsums = (int*)take(4096 * 4);
    int* btot = (int*)take(MAXBUK * 4);
    int* bbase = (int*)take(MAXBUK * 4);
    int* gcursor = (int*)take(MAXBUK * 4);
    unsigned* pairs = (unsigned*)take((size_t)E * 4);
    int* csr = (int*)take((size_t)(E + 3 * N + 256) * 4);
    float* hA = (float*)take((size_t)(N + 1) * CDIM * 4);
    float* hB = (float*)take((size_t)(N + 1) * CDIM * 4);
    unsigned* pooled = (unsigned*)take((size_t)G * CDIM * 4);
    (void)ws_size;
    (void)n_in;

    hipMemsetAsync(btot, 0, MAXBUK * 4, stream);
    hipMemsetAsync(pooled, 0, (size_t)G * CDIM * 4, stream);
    hipMemsetAsync(hA + (size_t)N * CDIM, 0, CDIM * 4, stream);  // zero row N
    hipMemsetAsync(hB + (size_t)N * CDIM, 0, CDIM * 4, stream);

    int NB = (N + 255) / 256;
    int CB = (E + CHUNK - 1) / CHUNK;

    bucket_count<<<CB, 256, 0, stream>>>(edst, btot, E, nbuk);
    bscan_kernel<<<1, 1024, 0, stream>>>(btot, bbase, gcursor, nbuk);
    bin_kernel<<<CB, 256, 0, stream>>>(esrc, edst, gcursor, pairs, E, nbuk);
    node_count<<<nbuk, 256, 0, stream>>>(pairs, bbase, btot, x_idx, cnt, dinvx, xi2, N);
    scan_reduce<<<NB, 256, 0, stream>>>(cnt, bsums, N);
    scan_bsums<<<1, 512, 0, stream>>>(bsums, NB);
    scan_final<<<NB, 256, 0, stream>>>(cnt, bsums, offsets4, N);
    csr_scatter<<<nbuk, 256, 0, stream>>>(pairs, bbase, btot, offsets4, csr, N);

    int LB = 2048;  // grid-stride; amortizes per-block weight preload
    gcn_layer<true><<<LB, 256, 0, stream>>>(
        nullptr, xi2, embed_w, dinvx, offsets4, cnt, csr,
        conv_w + 0 * CDIM * CDIM, conv_b + 0 * CDIM, hA, N, 1);
    gcn_layer<false><<<LB, 256, 0, stream>>>(
        hA, nullptr, nullptr, dinvx, offsets4, cnt, csr,
        conv_w + 1 * CDIM * CDIM, conv_b + 1 * CDIM, hB, N, 1);
    gcn_layer<false><<<LB, 256, 0, stream>>>(
        hB, nullptr, nullptr, dinvx, offsets4, cnt, csr,
        conv_w + 2 * CDIM * CDIM, conv_b + 2 * CDIM, hA, N, 1);
    gcn_layer<false><<<LB, 256, 0, stream>>>(
        hA, nullptr, nullptr, dinvx, offsets4, cnt, csr,
        conv_w + 3 * CDIM * CDIM, conv_b + 3 * CDIM, hB, N, 1);
    gcn_layer<false><<<LB, 256, 0, stream>>>(
        hB, nullptr, nullptr, dinvx, offsets4, cnt, csr,
        conv_w + 4 * CDIM * CDIM, conv_b + 4 * CDIM, hA, N, 0);

    int nchunks = (N + PCHUNK - 1) / PCHUNK;
    pool_kernel<<<(nchunks + 7) / 8, 256, 0, stream>>>(hA, batch, pooled, N);
    head_kernel<<<(G + 7) / 8, 256, 0, stream>>>((const float*)pooled, d0_w, d0_b,
                                                 dense_w, dense_b, fin_w, fin_b,
                                                 (float*)d_out, G);
}

// Round 7
// 386.501 us; speedup vs baseline: 1.1782x; 1.1782x over previous
//
#include <hip/hip_runtime.h>
#include <hip/hip_bf16.h>

// GCN forward: 5x (agg + linear + relu fused) + segment_max pool + MLP head.
// N=100000, E=1600000, C=32, G=128.
//
//  - CSR build via 2-level binning sort (bucket = dst>>7). NO per-node global
//    atomics anywhere:
//      bucket_count: per-chunk LDS hist (782 buckets) -> global btot adds.
//      bin_kernel:   LDS hist reserves contiguous per-(block,bucket) runs,
//                    writes packed (dstLocal<<20|src) pairs in ~64B runs.
//      node_count:   per bucket, LDS 128-ctr hist of pairs -> cnt/dinvx/xi2.
//      csr_scatter:  per bucket, LDS cursors from offsets4 -> csr (+pad to x4
//                    with index N, an all-zero feature row).
//  - features stored pre-scaled: ht[i] = dinv[i] * h[i]; ht[N] = 0.
//  - fused layer: 32-lane group per node; ONE 128B row per gather instruction
//    (32 lanes x 4B — the R6 quad-gather float4 layout blew HBM FETCH 10x and
//    regressed 30%; do not revisit). Manual 2x unroll of the int4 edge loop
//    gives 8 row-gathers in flight; dual accumulators + split matmul chains
//    shorten fp dependency chains. In-register 32x32 matmul via __shfl.
//  - pool: chunked running-max over sorted batch, uint atomicMax flush.
//  - head: 32-lane group per graph, float4 weight rows + __shfl matmul.

#define CDIM 32
#define BSHIFT 7
#define BSPAN 128
#define MAXBUK 800      // >= ceil(100000/128)=782
#define CHUNK 12800

// per-chunk LDS histogram of dst buckets -> btot
__global__ void __launch_bounds__(256) bucket_count(
    const int* __restrict__ edst, int* __restrict__ btot, int E, int nbuk) {
    __shared__ int hist[MAXBUK];
    int t = threadIdx.x;
    int base = blockIdx.x * CHUNK;
    int n = min(CHUNK, E - base);
    if (n <= 0) return;
    for (int i = t; i < nbuk; i += 256) hist[i] = 0;
    __syncthreads();
    for (int i = t; i < n; i += 256)
        atomicAdd(&hist[edst[base + i] >> BSHIFT], 1);
    __syncthreads();
    for (int b = t; b < nbuk; b += 256) {
        int h = hist[b];
        if (h) atomicAdd(&btot[b], h);
    }
}

// single block, 1024 threads; exclusive scan of btot -> bbase, gcursor
__global__ void bscan_kernel(const int* __restrict__ btot, int* __restrict__ bbase,
                             int* __restrict__ gcursor, int nb) {
    __shared__ int s[1024];
    int t = threadIdx.x;
    int v = (t < nb) ? btot[t] : 0;
    s[t] = v;
    __syncthreads();
    for (int d = 1; d < 1024; d <<= 1) {
        int x = (t >= d) ? s[t - d] : 0;
        __syncthreads();
        s[t] += x;
        __syncthreads();
    }
    if (t < nb) {
        bbase[t] = s[t] - v;
        gcursor[t] = s[t] - v;
    }
}

// bin edges by dst>>BSHIFT; contiguous per-(block,bucket) runs in pairs[]
__global__ void __launch_bounds__(256) bin_kernel(
    const int* __restrict__ esrc, const int* __restrict__ edst,
    int* __restrict__ gcursor, unsigned* __restrict__ pairs, int E, int nbuk) {
    __shared__ int hist[MAXBUK];
    __shared__ int lcur[MAXBUK];
    int t = threadIdx.x;
    int base = blockIdx.x * CHUNK;
    int n = min(CHUNK, E - base);
    if (n <= 0) return;
    for (int i = t; i < nbuk; i += 256) hist[i] = 0;
    __syncthreads();
    for (int i = t; i < n; i += 256)
        atomicAdd(&hist[edst[base + i] >> BSHIFT], 1);
    __syncthreads();
    for (int b = t; b < nbuk; b += 256) {
        int h = hist[b];
        lcur[b] = h ? atomicAdd(&gcursor[b], h) : 0;
    }
    __syncthreads();
    for (int i = t; i < n; i += 256) {
        int d = edst[base + i];
        int s = esrc[base + i];
        int b = d >> BSHIFT;
        int pos = atomicAdd(&lcur[b], 1);
        pairs[pos] = ((unsigned)(d & (BSPAN - 1)) << 20) | (unsigned)s;
    }
}

// per bucket: LDS histogram of dstLocal -> cnt, dinvx, xi2 (coalesced writes)
__global__ void __launch_bounds__(256) node_count(
    const unsigned* __restrict__ pairs, const int* __restrict__ bbase,
    const int* __restrict__ btot, const int* __restrict__ x_idx,
    int* __restrict__ cnt, float* __restrict__ dinvx, int* __restrict__ xi2,
    int N) {
    __shared__ int h[BSPAN];
    int b = blockIdx.x, t = threadIdx.x;
    if (t < BSPAN) h[t] = 0;
    __syncthreads();
    int p0 = bbase[b], p1 = p0 + btot[b];
    for (int i = p0 + t; i < p1; i += 256)
        atomicAdd(&h[pairs[i] >> 20], 1);
    __syncthreads();
    if (t < BSPAN) {
        int v = (b << BSHIFT) + t;
        if (v < N) {
            int c = h[t];
            cnt[v] = c;
            dinvx[v] = rsqrtf((float)c + 1.0f);
            xi2[v] = x_idx[v];
        }
    }
    if (b == 0 && t == 255) {  // sentinel row N
        dinvx[N] = 0.f;
        xi2[N] = 0;
    }
}

// padded-count scans: value = (cnt+3)&~3
__global__ void scan_reduce(const int* __restrict__ cnt, int* __restrict__ bsums, int N) {
    __shared__ int s[256];
    int t = threadIdx.x;
    int i = blockIdx.x * 256 + t;
    s[t] = (i < N) ? ((cnt[i] + 3) & ~3) : 0;
    __syncthreads();
    for (int d = 128; d > 0; d >>= 1) {
        if (t < d) s[t] += s[t + d];
        __syncthreads();
    }
    if (t == 0) bsums[blockIdx.x] = s[0];
}

__global__ void scan_bsums(int* bsums, int nb) {
    __shared__ int s[512];
    int t = threadIdx.x;
    int v = (t < nb) ? bsums[t] : 0;
    s[t] = v;
    __syncthreads();
    for (int d = 1; d < 512; d <<= 1) {
        int x = (t >= d) ? s[t - d] : 0;
        __syncthreads();
        s[t] += x;
        __syncthreads();
    }
    if (t < nb) bsums[t] = s[t] - v;  // exclusive
}

__global__ void scan_final(const int* __restrict__ cnt, const int* __restrict__ bsums,
                           int* __restrict__ offsets4, int N) {
    __shared__ int s[256];
    int t = threadIdx.x;
    int i = blockIdx.x * 256 + t;
    int v = (i < N) ? ((cnt[i] + 3) & ~3) : 0;
    s[t] = v;
    __syncthreads();
    for (int d = 1; d < 256; d <<= 1) {
        int x = (t >= d) ? s[t - d] : 0;
        __syncthreads();
        s[t] += x;
        __syncthreads();
    }
    if (i < N) offsets4[i] = s[t] - v + bsums[blockIdx.x];
}

// per bucket: scatter src into padded CSR via LDS cursors; pad to x4 with N
__global__ void __launch_bounds__(256) csr_scatter(
    const unsigned* __restrict__ pairs, const int* __restrict__ bbase,
    const int* __restrict__ btot, const int* __restrict__ offsets4,
    int* __restrict__ csr, int N) {
    __shared__ int lcur[BSPAN];
    __shared__ int obase[BSPAN];
    int b = blockIdx.x, t = threadIdx.x;
    int v0 = b << BSHIFT;
    if (t < BSPAN) {
        int v = v0 + t;
        int o = (v < N) ? offsets4[v] : 0;
        lcur[t] = o;
        obase[t] = o;
    }
    __syncthreads();
    int p0 = bbase[b], p1 = p0 + btot[b];
    for (int i = p0 + t; i < p1; i += 256) {
        unsigned pk = pairs[i];
        int pos = atomicAdd(&lcur[pk >> 20], 1);
        csr[pos] = (int)(pk & 0xFFFFFu);
    }
    __syncthreads();
    if (t < BSPAN) {
        int v = v0 + t;
        if (v < N) {
            int e = lcur[t];  // == offsets4[v] + cnt[v]
            int e1 = obase[t] + ((e - obase[t] + 3) & ~3);
            for (; e < e1; ++e) csr[e] = N;  // pad -> zero feature row
        }
    }
}

// Fused GCN layer. 32-lane group per node; one 128B row per gather inst.
// Manual 2x unroll: 8 row gathers in flight; dual accumulators.
template <bool L1>
__global__ void __launch_bounds__(256) gcn_layer(
    const float* __restrict__ ht, const int* __restrict__ xi2,
    const float* __restrict__ ew, const float* __restrict__ dinvx,
    const int* __restrict__ offsets4, const int* __restrict__ cnt,
    const int* __restrict__ csr, const float* __restrict__ W,
    const float* __restrict__ bias, float* __restrict__ out,
    int N, int scale_next) {
    int c = threadIdx.x & 31;
    int grp = threadIdx.x >> 5;  // 0..7

    float w[CDIM];
    {
        const float4* Wrow = reinterpret_cast<const float4*>(W + c * CDIM);
        #pragma unroll
        for (int q = 0; q < CDIM / 4; ++q) {
            float4 t = Wrow[q];
            w[4 * q + 0] = t.x;
            w[4 * q + 1] = t.y;
            w[4 * q + 2] = t.z;
            w[4 * q + 3] = t.w;
        }
    }
    float bc = bias[c];

    for (int v0 = blockIdx.x * 8; v0 < N; v0 += gridDim.x * 8) {
        int v = v0 + grp;
        if (v >= N) continue;  // uniform across the 32-lane group
        float dv = dinvx[v];
        float acc0, acc1 = 0.f;
        if (L1)
            acc0 = dv * ew[xi2[v] * CDIM + c];
        else
            acc0 = ht[v * CDIM + c];
        int e = offsets4[v];
        int nq = (cnt[v] + 3) >> 2;  // quads (csr padded to x4 with sentinel N)
        while (nq >= 2) {  // 8 edges: 2 int4 index loads + 8 row gathers in flight
            int4 a = *reinterpret_cast<const int4*>(&csr[e]);
            int4 b = *reinterpret_cast<const int4*>(&csr[e + 4]);
            if (L1) {
                float f0 = dinvx[a.x] * ew[xi2[a.x] * CDIM + c];
                float f1 = dinvx[a.y] * ew[xi2[a.y] * CDIM + c];
                float f2 = dinvx[a.z] * ew[xi2[a.z] * CDIM + c];
                float f3 = dinvx[a.w] * ew[xi2[a.w] * CDIM + c];
                float f4 = dinvx[b.x] * ew[xi2[b.x] * CDIM + c];
                float f5 = dinvx[b.y] * ew[xi2[b.y] * CDIM + c];
                float f6 = dinvx[b.z] * ew[xi2[b.z] * CDIM + c];
                float f7 = dinvx[b.w] * ew[xi2[b.w] * CDIM + c];
                acc0 += (f0 + f1) + (f2 + f3);
                acc1 += (f4 + f5) + (f6 + f7);
            } else {
                float f0 = ht[a.x * CDIM + c];
                float f1 = ht[a.y * CDIM + c];
                float f2 = ht[a.z * CDIM + c];
                float f3 = ht[a.w * CDIM + c];
                float f4 = ht[b.x * CDIM + c];
                float f5 = ht[b.y * CDIM + c];
                float f6 = ht[b.z * CDIM + c];
                float f7 = ht[b.w * CDIM + c];
                acc0 += (f0 + f1) + (f2 + f3);
                acc1 += (f4 + f5) + (f6 + f7);
            }
            e += 8;
            nq -= 2;
        }
        if (nq) {
            int4 a = *reinterpret_cast<const int4*>(&csr[e]);
            if (L1) {
                float f0 = dinvx[a.x] * ew[xi2[a.x] * CDIM + c];
                float f1 = dinvx[a.y] * ew[xi2[a.y] * CDIM + c];
                float f2 = dinvx[a.z] * ew[xi2[a.z] * CDIM + c];
                float f3 = dinvx[a.w] * ew[xi2[a.w] * CDIM + c];
                acc1 += (f0 + f1) + (f2 + f3);
            } else {
                float f0 = ht[a.x * CDIM + c];
                float f1 = ht[a.y * CDIM + c];
                float f2 = ht[a.z * CDIM + c];
                float f3 = ht[a.w * CDIM + c];
                acc1 += (f0 + f1) + (f2 + f3);
            }
        }
        float aggv = dv * (acc0 + acc1);  // true aggregation value, channel c
        // 32x32 matmul via shfl broadcast; two chains to halve dep latency
        float o0 = bc, o1 = 0.f;
        #pragma unroll
        for (int k = 0; k < CDIM; k += 2) {
            o0 = fmaf(__shfl(aggv, k, 32), w[k], o0);
            o1 = fmaf(__shfl(aggv, k + 1, 32), w[k + 1], o1);
        }
        float o = fmaxf(o0 + o1, 0.f);
        if (scale_next) o *= dv;
        out[v * CDIM + c] = o;
    }
}

// chunked segment-max over sorted batch; h >= 0 so uint-bit atomicMax is valid
#define PCHUNK 128
__global__ void pool_kernel(const float* __restrict__ h, const int* __restrict__ batch,
                            unsigned* __restrict__ pooled, int N) {
    __shared__ int sb[8 * PCHUNK];
    int t = threadIdx.x;
    int chunk0 = blockIdx.x * 8;
    int sbase = chunk0 * PCHUNK;
    for (int i = t; i < 8 * PCHUNK; i += 256)
        sb[i] = (sbase + i < N) ? batch[sbase + i] : -1;
    __syncthreads();
    int c = t & 31, cs = t >> 5;
    int i0 = (chunk0 + cs) * PCHUNK;
    if (i0 >= N) return;
    int curg = sb[cs * PCHUNK];
    float m = -1.0f;  // sentinel: nothing accumulated (h values are >= 0)
    for (int k = 0; k < PCHUNK; ++k) {
        int i = i0 + k;
        if (i >= N) break;
        int g = sb[cs * PCHUNK + k];
        float v = h[i * CDIM + c];
        if (g != curg) {
            if (m >= 0.f) atomicMax(&pooled[curg * CDIM + c], __float_as_uint(m));
            curg = g;
            m = v;
        } else {
            m = fmaxf(m, v);
        }
    }
    if (m >= 0.f && curg >= 0) atomicMax(&pooled[curg * CDIM + c], __float_as_uint(m));
}

// 32-lane group per graph; coalesced float4 weight rows + __shfl matmul.
__global__ void __launch_bounds__(256) head_kernel(
    const float* __restrict__ pooled,
    const float* __restrict__ d0_w, const float* __restrict__ d0_b,
    const float* __restrict__ dense_w, const float* __restrict__ dense_b,
    const float* __restrict__ fin_w, const float* __restrict__ fin_b,
    float* __restrict__ out, int G) {
    int c = threadIdx.x & 31;
    int grp = threadIdx.x >> 5;
    int g = blockIdx.x * 8 + grp;
    if (g >= G) return;

    float x = pooled[g * CDIM + c];  // lane c holds channel c

    const float* Ws[4] = {d0_w, dense_w, dense_w + CDIM * CDIM,
                          dense_w + 2 * CDIM * CDIM};
    const float* bs[4] = {d0_b, dense_b, dense_b + CDIM, dense_b + 2 * CDIM};
    for (int l = 0; l < 4; ++l) {
        float w[CDIM];
        const float4* Wrow = reinterpret_cast<const float4*>(Ws[l] + c * CDIM);
        #pragma unroll
        for (int q = 0; q < CDIM / 4; ++q) {
            float4 t = Wrow[q];
            w[4 * q + 0] = t.x;
            w[4 * q + 1] = t.y;
            w[4 * q + 2] = t.z;
            w[4 * q + 3] = t.w;
        }
        float acc = bs[l][c];
        #pragma unroll
        for (int k = 0; k < CDIM; ++k)
            acc = fmaf(__shfl(x, k, 32), w[k], acc);
        x = fmaxf(acc, 0.f);
    }
    // logits: butterfly reduce partial products across the 32-lane group
    float p0 = x * fin_w[c];
    float p1 = x * fin_w[CDIM + c];
    #pragma unroll
    for (int d = 16; d > 0; d >>= 1) {
        p0 += __shfl_xor(p0, d, 32);
        p1 += __shfl_xor(p1, d, 32);
    }
    float l0 = p0 + fin_b[0], l1 = p1 + fin_b[1];
    float mm = fmaxf(l0, l1);
    float lse = mm + logf(expf(l0 - mm) + expf(l1 - mm));
    if (c == 0) {
        out[g * 2 + 0] = l0 - lse;
        out[g * 2 + 1] = l1 - lse;
    }
}

extern "C" void kernel_launch(void* const* d_in, const int* in_sizes, int n_in,
                              void* d_out, int out_size, void* d_ws, size_t ws_size,
                              hipStream_t stream) {
    const int* x_idx = (const int*)d_in[0];
    const int* eidx = (const int*)d_in[1];
    const int* batch = (const int*)d_in[2];
    const float* embed_w = (const float*)d_in[3];
    const float* conv_w = (const float*)d_in[4];
    const float* conv_b = (const float*)d_in[5];
    const float* d0_w = (const float*)d_in[6];
    const float* d0_b = (const float*)d_in[7];
    const float* dense_w = (const float*)d_in[8];
    const float* dense_b = (const float*)d_in[9];
    const float* fin_w = (const float*)d_in[10];
    const float* fin_b = (const float*)d_in[11];

    int N = in_sizes[0];
    int E = in_sizes[1] / 2;
    int G = out_size / 2;
    const int* esrc = eidx;
    const int* edst = eidx + E;
    int nbuk = (N + BSPAN - 1) >> BSHIFT;  // 782

    char* ws = (char*)d_ws;
    size_t off = 0;
    auto take = [&](size_t bytes) -> char* {
        char* p = ws + off;
        off = (off + bytes + 255) & ~(size_t)255;
        return p;
    };
    int* cnt = (int*)take((size_t)N * 4);
    float* dinvx = (float*)take((size_t)(N + 1) * 4);
    int* xi2 = (int*)take((size_t)(N + 1) * 4);
    int* offsets4 = (int*)take((size_t)N * 4);
    int* bsums = (int*)take(4096 * 4);
    int* btot = (int*)take(MAXBUK * 4);
    int* bbase = (int*)take(MAXBUK * 4);
    int* gcursor = (int*)take(MAXBUK * 4);
    unsigned* pairs = (unsigned*)take((size_t)E * 4);
    int* csr = (int*)take((size_t)(E + 3 * N + 256) * 4);
    float* hA = (float*)take((size_t)(N + 1) * CDIM * 4);
    float* hB = (float*)take((size_t)(N + 1) * CDIM * 4);
    unsigned* pooled = (unsigned*)take((size_t)G * CDIM * 4);
    (void)ws_size;
    (void)n_in;

    hipMemsetAsync(btot, 0, MAXBUK * 4, stream);
    hipMemsetAsync(pooled, 0, (size_t)G * CDIM * 4, stream);
    hipMemsetAsync(hA + (size_t)N * CDIM, 0, CDIM * 4, stream);  // zero row N
    hipMemsetAsync(hB + (size_t)N * CDIM, 0, CDIM * 4, stream);

    int NB = (N + 255) / 256;
    int CB = (E + CHUNK - 1) / CHUNK;

    bucket_count<<<CB, 256, 0, stream>>>(edst, btot, E, nbuk);
    bscan_kernel<<<1, 1024, 0, stream>>>(btot, bbase, gcursor, nbuk);
    bin_kernel<<<CB, 256, 0, stream>>>(esrc, edst, gcursor, pairs, E, nbuk);
    node_count<<<nbuk, 256, 0, stream>>>(pairs, bbase, btot, x_idx, cnt, dinvx, xi2, N);
    scan_reduce<<<NB, 256, 0, stream>>>(cnt, bsums, N);
    scan_bsums<<<1, 512, 0, stream>>>(bsums, NB);
    scan_final<<<NB, 256, 0, stream>>>(cnt, bsums, offsets4, N);
    csr_scatter<<<nbuk, 256, 0, stream>>>(pairs, bbase, btot, offsets4, csr, N);

    int LB = 2048;  // grid-stride; amortizes per-block weight preload
    gcn_layer<true><<<LB, 256, 0, stream>>>(
        nullptr, xi2, embed_w, dinvx, offsets4, cnt, csr,
        conv_w + 0 * CDIM * CDIM, conv_b + 0 * CDIM, hA, N, 1);
    gcn_layer<false><<<LB, 256, 0, stream>>>(
        hA, nullptr, nullptr, dinvx, offsets4, cnt, csr,
        conv_w + 1 * CDIM * CDIM, conv_b + 1 * CDIM, hB, N, 1);
    gcn_layer<false><<<LB, 256, 0, stream>>>(
        hB, nullptr, nullptr, dinvx, offsets4, cnt, csr,
        conv_w + 2 * CDIM * CDIM, conv_b + 2 * CDIM, hA, N, 1);
    gcn_layer<false><<<LB, 256, 0, stream>>>(
        hA, nullptr, nullptr, dinvx, offsets4, cnt, csr,
        conv_w + 3 * CDIM * CDIM, conv_b + 3 * CDIM, hB, N, 1);
    gcn_layer<false><<<LB, 256, 0, stream>>>(
        hB, nullptr, nullptr, dinvx, offsets4, cnt, csr,
        conv_w + 4 * CDIM * CDIM, conv_b + 4 * CDIM, hA, N, 0);

    int nchunks = (N + PCHUNK - 1) / PCHUNK;
    pool_kernel<<<(nchunks + 7) / 8, 256, 0, stream>>>(hA, batch, pooled, N);
    head_kernel<<<(G + 7) / 8, 256, 0, stream>>>((const float*)pooled, d0_w, d0_b,
                                                 dense_w, dense_b, fin_w, fin_b,
                                                 (float*)d_out, G);
}

// Round 8
// 341.758 us; speedup vs baseline: 1.3325x; 1.1309x over previous
//
#include <hip/hip_runtime.h>
#include <hip/hip_bf16.h>
#include <hip/hip_fp16.h>

// GCN forward: 5x (agg + linear + relu fused) + segment_max pool + MLP head.
// N=100000, E=1600000, C=32, G=128.
//
//  - CSR build via 2-level binning sort (bucket = dst>>7). NO per-node global
//    atomics anywhere (bucket_count / bin_kernel / node_count / csr_scatter).
//  - Node features stored PRE-SCALED by dinv in FP16 (6.4MB, ~62% of an XCD
//    L2): ht[i] = dinv[i]*h[i]; row = 64B = one cache line per gather. Math
//    stays fp32 (convert on load/store).
//  - gcn_layer: 32-lane group per node; one int4 index load -> 4 independent
//    one-line row gathers (R5-proven shape; R6 float4 multi-row gathers blew
//    HBM FETCH 10x, R7 manual unroll broke scheduling — do not revisit).
//    In-register 32x32 matmul via __shfl, relu, dinv pre-scale for next layer.
//  - embed_half materializes dinv*embed_w[x_idx] once so all 5 layers run the
//    identical lean loop (no per-edge dinv/x_idx side-loads).
//  - pool: chunked running-max over sorted batch, uint atomicMax flush.
//  - head: 32-lane group per graph, float4 weight rows + __shfl matmul.

#define CDIM 32
#define BSHIFT 7
#define BSPAN 128
#define MAXBUK 800      // >= ceil(100000/128)=782
#define CHUNK 12800

// per-chunk LDS histogram of dst buckets -> btot
__global__ void __launch_bounds__(256) bucket_count(
    const int* __restrict__ edst, int* __restrict__ btot, int E, int nbuk) {
    __shared__ int hist[MAXBUK];
    int t = threadIdx.x;
    int base = blockIdx.x * CHUNK;
    int n = min(CHUNK, E - base);
    if (n <= 0) return;
    for (int i = t; i < nbuk; i += 256) hist[i] = 0;
    __syncthreads();
    for (int i = t; i < n; i += 256)
        atomicAdd(&hist[edst[base + i] >> BSHIFT], 1);
    __syncthreads();
    for (int b = t; b < nbuk; b += 256) {
        int h = hist[b];
        if (h) atomicAdd(&btot[b], h);
    }
}

// single block, 1024 threads; exclusive scan of btot -> bbase, gcursor
__global__ void bscan_kernel(const int* __restrict__ btot, int* __restrict__ bbase,
                             int* __restrict__ gcursor, int nb) {
    __shared__ int s[1024];
    int t = threadIdx.x;
    int v = (t < nb) ? btot[t] : 0;
    s[t] = v;
    __syncthreads();
    for (int d = 1; d < 1024; d <<= 1) {
        int x = (t >= d) ? s[t - d] : 0;
        __syncthreads();
        s[t] += x;
        __syncthreads();
    }
    if (t < nb) {
        bbase[t] = s[t] - v;
        gcursor[t] = s[t] - v;
    }
}

// bin edges by dst>>BSHIFT; contiguous per-(block,bucket) runs in pairs[]
__global__ void __launch_bounds__(256) bin_kernel(
    const int* __restrict__ esrc, const int* __restrict__ edst,
    int* __restrict__ gcursor, unsigned* __restrict__ pairs, int E, int nbuk) {
    __shared__ int hist[MAXBUK];
    __shared__ int lcur[MAXBUK];
    int t = threadIdx.x;
    int base = blockIdx.x * CHUNK;
    int n = min(CHUNK, E - base);
    if (n <= 0) return;
    for (int i = t; i < nbuk; i += 256) hist[i] = 0;
    __syncthreads();
    for (int i = t; i < n; i += 256)
        atomicAdd(&hist[edst[base + i] >> BSHIFT], 1);
    __syncthreads();
    for (int b = t; b < nbuk; b += 256) {
        int h = hist[b];
        lcur[b] = h ? atomicAdd(&gcursor[b], h) : 0;
    }
    __syncthreads();
    for (int i = t; i < n; i += 256) {
        int d = edst[base + i];
        int s = esrc[base + i];
        int b = d >> BSHIFT;
        int pos = atomicAdd(&lcur[b], 1);
        pairs[pos] = ((unsigned)(d & (BSPAN - 1)) << 20) | (unsigned)s;
    }
}

// per bucket: LDS histogram of dstLocal -> cnt, dinvx (coalesced writes)
__global__ void __launch_bounds__(256) node_count(
    const unsigned* __restrict__ pairs, const int* __restrict__ bbase,
    const int* __restrict__ btot,
    int* __restrict__ cnt, float* __restrict__ dinvx, int N) {
    __shared__ int h[BSPAN];
    int b = blockIdx.x, t = threadIdx.x;
    if (t < BSPAN) h[t] = 0;
    __syncthreads();
    int p0 = bbase[b], p1 = p0 + btot[b];
    for (int i = p0 + t; i < p1; i += 256)
        atomicAdd(&h[pairs[i] >> 20], 1);
    __syncthreads();
    if (t < BSPAN) {
        int v = (b << BSHIFT) + t;
        if (v < N) {
            int c = h[t];
            cnt[v] = c;
            dinvx[v] = rsqrtf((float)c + 1.0f);
        }
    }
    if (b == 0 && t == 255) dinvx[N] = 0.f;  // sentinel
}

// padded-count scans: value = (cnt+3)&~3
__global__ void scan_reduce(const int* __restrict__ cnt, int* __restrict__ bsums, int N) {
    __shared__ int s[256];
    int t = threadIdx.x;
    int i = blockIdx.x * 256 + t;
    s[t] = (i < N) ? ((cnt[i] + 3) & ~3) : 0;
    __syncthreads();
    for (int d = 128; d > 0; d >>= 1) {
        if (t < d) s[t] += s[t + d];
        __syncthreads();
    }
    if (t == 0) bsums[blockIdx.x] = s[0];
}

__global__ void scan_bsums(int* bsums, int nb) {
    __shared__ int s[512];
    int t = threadIdx.x;
    int v = (t < nb) ? bsums[t] : 0;
    s[t] = v;
    __syncthreads();
    for (int d = 1; d < 512; d <<= 1) {
        int x = (t >= d) ? s[t - d] : 0;
        __syncthreads();
        s[t] += x;
        __syncthreads();
    }
    if (t < nb) bsums[t] = s[t] - v;  // exclusive
}

__global__ void scan_final(const int* __restrict__ cnt, const int* __restrict__ bsums,
                           int* __restrict__ offsets4, int N) {
    __shared__ int s[256];
    int t = threadIdx.x;
    int i = blockIdx.x * 256 + t;
    int v = (i < N) ? ((cnt[i] + 3) & ~3) : 0;
    s[t] = v;
    __syncthreads();
    for (int d = 1; d < 256; d <<= 1) {
        int x = (t >= d) ? s[t - d] : 0;
        __syncthreads();
        s[t] += x;
        __syncthreads();
    }
    if (i < N) offsets4[i] = s[t] - v + bsums[blockIdx.x];
}

// per bucket: scatter src into padded CSR via LDS cursors; pad to x4 with N
__global__ void __launch_bounds__(256) csr_scatter(
    const unsigned* __restrict__ pairs, const int* __restrict__ bbase,
    const int* __restrict__ btot, const int* __restrict__ offsets4,
    int* __restrict__ csr, int N) {
    __shared__ int lcur[BSPAN];
    __shared__ int obase[BSPAN];
    int b = blockIdx.x, t = threadIdx.x;
    int v0 = b << BSHIFT;
    if (t < BSPAN) {
        int v = v0 + t;
        int o = (v < N) ? offsets4[v] : 0;
        lcur[t] = o;
        obase[t] = o;
    }
    __syncthreads();
    int p0 = bbase[b], p1 = p0 + btot[b];
    for (int i = p0 + t; i < p1; i += 256) {
        unsigned pk = pairs[i];
        int pos = atomicAdd(&lcur[pk >> 20], 1);
        csr[pos] = (int)(pk & 0xFFFFFu);
    }
    __syncthreads();
    if (t < BSPAN) {
        int v = v0 + t;
        if (v < N) {
            int e = lcur[t];  // == offsets4[v] + cnt[v]
            int e1 = obase[t] + ((e - obase[t] + 3) & ~3);
            for (; e < e1; ++e) csr[e] = N;  // pad -> zero feature row
        }
    }
}

// hE[i][c] = dinv[i] * embed_w[x_idx[i]][c], stored fp16 (pre-scaled layer-1 input)
__global__ void embed_half(const int* __restrict__ x_idx, const float* __restrict__ ew,
                           const float* __restrict__ dinvx, __half* __restrict__ h, int N) {
    int tid = blockIdx.x * 256 + threadIdx.x;
    int i = tid >> 5, c = tid & 31;
    if (i >= N) return;
    h[tid] = __float2half(dinvx[i] * ew[x_idx[i] * CDIM + c]);
}

// Fused GCN layer (R5-proven shape). 32-lane group per node; fp16 features,
// fp32 math. One int4 index load -> 4 independent one-line row gathers.
__global__ void __launch_bounds__(256) gcn_layer(
    const __half* __restrict__ ht, const float* __restrict__ dinvx,
    const int* __restrict__ offsets4, const int* __restrict__ cnt,
    const int* __restrict__ csr, const float* __restrict__ W,
    const float* __restrict__ bias, __half* __restrict__ out,
    int N, int scale_next) {
    int c = threadIdx.x & 31;
    int grp = threadIdx.x >> 5;  // 0..7

    float w[CDIM];
    {
        const float4* Wrow = reinterpret_cast<const float4*>(W + c * CDIM);
        #pragma unroll
        for (int q = 0; q < CDIM / 4; ++q) {
            float4 t = Wrow[q];
            w[4 * q + 0] = t.x;
            w[4 * q + 1] = t.y;
            w[4 * q + 2] = t.z;
            w[4 * q + 3] = t.w;
        }
    }
    float bc = bias[c];

    for (int v0 = blockIdx.x * 8; v0 < N; v0 += gridDim.x * 8) {
        int v = v0 + grp;
        if (v >= N) continue;  // uniform across the 32-lane group
        float dv = dinvx[v];
        float acc = __half2float(ht[v * CDIM + c]);
        int e = offsets4[v];
        int e1 = e + ((cnt[v] + 3) & ~3);
        for (; e < e1; e += 4) {
            int4 s4 = *reinterpret_cast<const int4*>(&csr[e]);
            float a0 = __half2float(ht[s4.x * CDIM + c]);
            float a1 = __half2float(ht[s4.y * CDIM + c]);
            float a2 = __half2float(ht[s4.z * CDIM + c]);
            float a3 = __half2float(ht[s4.w * CDIM + c]);
            acc += (a0 + a1) + (a2 + a3);
        }
        float aggv = dv * acc;  // true aggregation value, channel c
        float o = bc;
        #pragma unroll
        for (int k = 0; k < CDIM; ++k)
            o = fmaf(__shfl(aggv, k, 32), w[k], o);
        o = fmaxf(o, 0.f);
        if (scale_next) o *= dv;
        out[v * CDIM + c] = __float2half(o);
    }
}

// chunked segment-max over sorted batch; h >= 0 so uint-bit atomicMax is valid
#define PCHUNK 128
__global__ void pool_kernel(const __half* __restrict__ h, const int* __restrict__ batch,
                            unsigned* __restrict__ pooled, int N) {
    __shared__ int sb[8 * PCHUNK];
    int t = threadIdx.x;
    int chunk0 = blockIdx.x * 8;
    int sbase = chunk0 * PCHUNK;
    for (int i = t; i < 8 * PCHUNK; i += 256)
        sb[i] = (sbase + i < N) ? batch[sbase + i] : -1;
    __syncthreads();
    int c = t & 31, cs = t >> 5;
    int i0 = (chunk0 + cs) * PCHUNK;
    if (i0 >= N) return;
    int curg = sb[cs * PCHUNK];
    float m = -1.0f;  // sentinel: nothing accumulated (h values are >= 0)
    for (int k = 0; k < PCHUNK; ++k) {
        int i = i0 + k;
        if (i >= N) break;
        int g = sb[cs * PCHUNK + k];
        float v = __half2float(h[i * CDIM + c]);
        if (g != curg) {
            if (m >= 0.f) atomicMax(&pooled[curg * CDIM + c], __float_as_uint(m));
            curg = g;
            m = v;
        } else {
            m = fmaxf(m, v);
        }
    }
    if (m >= 0.f && curg >= 0) atomicMax(&pooled[curg * CDIM + c], __float_as_uint(m));
}

// 32-lane group per graph; coalesced float4 weight rows + __shfl matmul.
__global__ void __launch_bounds__(256) head_kernel(
    const float* __restrict__ pooled,
    const float* __restrict__ d0_w, const float* __restrict__ d0_b,
    const float* __restrict__ dense_w, const float* __restrict__ dense_b,
    const float* __restrict__ fin_w, const float* __restrict__ fin_b,
    float* __restrict__ out, int G) {
    int c = threadIdx.x & 31;
    int grp = threadIdx.x >> 5;
    int g = blockIdx.x * 8 + grp;
    if (g >= G) return;

    float x = pooled[g * CDIM + c];  // lane c holds channel c

    const float* Ws[4] = {d0_w, dense_w, dense_w + CDIM * CDIM,
                          dense_w + 2 * CDIM * CDIM};
    const float* bs[4] = {d0_b, dense_b, dense_b + CDIM, dense_b + 2 * CDIM};
    for (int l = 0; l < 4; ++l) {
        float w[CDIM];
        const float4* Wrow = reinterpret_cast<const float4*>(Ws[l] + c * CDIM);
        #pragma unroll
        for (int q = 0; q < CDIM / 4; ++q) {
            float4 t = Wrow[q];
            w[4 * q + 0] = t.x;
            w[4 * q + 1] = t.y;
            w[4 * q + 2] = t.z;
            w[4 * q + 3] = t.w;
        }
        float acc = bs[l][c];
        #pragma unroll
        for (int k = 0; k < CDIM; ++k)
            acc = fmaf(__shfl(x, k, 32), w[k], acc);
        x = fmaxf(acc, 0.f);
    }
    // logits: butterfly reduce partial products across the 32-lane group
    float p0 = x * fin_w[c];
    float p1 = x * fin_w[CDIM + c];
    #pragma unroll
    for (int d = 16; d > 0; d >>= 1) {
        p0 += __shfl_xor(p0, d, 32);
        p1 += __shfl_xor(p1, d, 32);
    }
    float l0 = p0 + fin_b[0], l1 = p1 + fin_b[1];
    float mm = fmaxf(l0, l1);
    float lse = mm + logf(expf(l0 - mm) + expf(l1 - mm));
    if (c == 0) {
        out[g * 2 + 0] = l0 - lse;
        out[g * 2 + 1] = l1 - lse;
    }
}

extern "C" void kernel_launch(void* const* d_in, const int* in_sizes, int n_in,
                              void* d_out, int out_size, void* d_ws, size_t ws_size,
                              hipStream_t stream) {
    const int* x_idx = (const int*)d_in[0];
    const int* eidx = (const int*)d_in[1];
    const int* batch = (const int*)d_in[2];
    const float* embed_w = (const float*)d_in[3];
    const float* conv_w = (const float*)d_in[4];
    const float* conv_b = (const float*)d_in[5];
    const float* d0_w = (const float*)d_in[6];
    const float* d0_b = (const float*)d_in[7];
    const float* dense_w = (const float*)d_in[8];
    const float* dense_b = (const float*)d_in[9];
    const float* fin_w = (const float*)d_in[10];
    const float* fin_b = (const float*)d_in[11];

    int N = in_sizes[0];
    int E = in_sizes[1] / 2;
    int G = out_size / 2;
    const int* esrc = eidx;
    const int* edst = eidx + E;
    int nbuk = (N + BSPAN - 1) >> BSHIFT;  // 782

    char* ws = (char*)d_ws;
    size_t off = 0;
    auto take = [&](size_t bytes) -> char* {
        char* p = ws + off;
        off = (off + bytes + 255) & ~(size_t)255;
        return p;
    };
    int* cnt = (int*)take((size_t)N * 4);
    float* dinvx = (float*)take((size_t)(N + 1) * 4);
    int* offsets4 = (int*)take((size_t)N * 4);
    int* bsums = (int*)take(4096 * 4);
    int* btot = (int*)take(MAXBUK * 4);
    int* bbase = (int*)take(MAXBUK * 4);
    int* gcursor = (int*)take(MAXBUK * 4);
    unsigned* pairs = (unsigned*)take((size_t)E * 4);
    int* csr = (int*)take((size_t)(E + 3 * N + 256) * 4);
    __half* hA = (__half*)take((size_t)(N + 1) * CDIM * 2);
    __half* hB = (__half*)take((size_t)(N + 1) * CDIM * 2);
    unsigned* pooled = (unsigned*)take((size_t)G * CDIM * 4);
    (void)ws_size;
    (void)n_in;

    hipMemsetAsync(btot, 0, MAXBUK * 4, stream);
    hipMemsetAsync(pooled, 0, (size_t)G * CDIM * 4, stream);
    hipMemsetAsync(hA + (size_t)N * CDIM, 0, CDIM * 2, stream);  // zero row N
    hipMemsetAsync(hB + (size_t)N * CDIM, 0, CDIM * 2, stream);

    int NB = (N + 255) / 256;
    int CB = (E + CHUNK - 1) / CHUNK;

    bucket_count<<<CB, 256, 0, stream>>>(edst, btot, E, nbuk);
    bscan_kernel<<<1, 1024, 0, stream>>>(btot, bbase, gcursor, nbuk);
    bin_kernel<<<CB, 256, 0, stream>>>(esrc, edst, gcursor, pairs, E, nbuk);
    node_count<<<nbuk, 256, 0, stream>>>(pairs, bbase, btot, cnt, dinvx, N);
    scan_reduce<<<NB, 256, 0, stream>>>(cnt, bsums, N);
    scan_bsums<<<1, 512, 0, stream>>>(bsums, NB);
    scan_final<<<NB, 256, 0, stream>>>(cnt, bsums, offsets4, N);
    csr_scatter<<<nbuk, 256, 0, stream>>>(pairs, bbase, btot, offsets4, csr, N);

    embed_half<<<(N * CDIM + 255) / 256, 256, 0, stream>>>(x_idx, embed_w, dinvx, hA, N);

    int LB = 2048;  // grid-stride; amortizes per-block weight preload
    gcn_layer<<<LB, 256, 0, stream>>>(hA, dinvx, offsets4, cnt, csr,
                                      conv_w + 0 * CDIM * CDIM, conv_b + 0 * CDIM, hB, N, 1);
    gcn_layer<<<LB, 256, 0, stream>>>(hB, dinvx, offsets4, cnt, csr,
                                      conv_w + 1 * CDIM * CDIM, conv_b + 1 * CDIM, hA, N, 1);
    gcn_layer<<<LB, 256, 0, stream>>>(hA, dinvx, offsets4, cnt, csr,
                                      conv_w + 2 * CDIM * CDIM, conv_b + 2 * CDIM, hB, N, 1);
    gcn_layer<<<LB, 256, 0, stream>>>(hB, dinvx, offsets4, cnt, csr,
                                      conv_w + 3 * CDIM * CDIM, conv_b + 3 * CDIM, hA, N, 1);
    gcn_layer<<<LB, 256, 0, stream>>>(hA, dinvx, offsets4, cnt, csr,
                                      conv_w + 4 * CDIM * CDIM, conv_b + 4 * CDIM, hB, N, 0);

    int nchunks = (N + PCHUNK - 1) / PCHUNK;
    pool_kernel<<<(nchunks + 7) / 8, 256, 0, stream>>>(hB, batch, pooled, N);
    head_kernel<<<(G + 7) / 8, 256, 0, stream>>>((const float*)pooled, d0_w, d0_b,
                                                 dense_w, dense_b, fin_w, fin_b,
                                                 (float*)d_out, G);
}